// Round 1
// baseline (1891.858 us; speedup 1.0000x reference)
//
#include <hip/hip_runtime.h>
#include <hip/hip_bf16.h>
#include <math.h>

#define B_ 4
#define L_ 2048
#define DIM_ 256
#define DST_ 16
#define DCONV_ 4
#define DIN_ 512   // D_INNER
#define DTR_ 16    // DT_RANK

// ---------------- LayerNorm: one block (256 thr) per row ----------------
__global__ __launch_bounds__(256) void ln_k(const float* __restrict__ x,
                                            const float* __restrict__ g,
                                            const float* __restrict__ b,
                                            float* __restrict__ out) {
  int row = blockIdx.x;
  int t = threadIdx.x;
  float v = x[(size_t)row * DIM_ + t];
  float s = v, s2 = v * v;
  #pragma unroll
  for (int off = 32; off; off >>= 1) {
    s += __shfl_down(s, off);
    s2 += __shfl_down(s2, off);
  }
  __shared__ float ss[4], ss2[4];
  int w = t >> 6;
  if ((t & 63) == 0) { ss[w] = s; ss2[w] = s2; }
  __syncthreads();
  if (t == 0) {
    float S = ss[0] + ss[1] + ss[2] + ss[3];
    float S2 = ss2[0] + ss2[1] + ss2[2] + ss2[3];
    float mu = S * (1.f / DIM_);
    float var = S2 * (1.f / DIM_) - mu * mu;
    ss[0] = mu;
    ss2[0] = rsqrtf(var + 1e-5f);
  }
  __syncthreads();
  float mu = ss[0], rs = ss2[0];
  out[(size_t)row * DIM_ + t] = (v - mu) * rs * g[t] + b[t];
}

// ---------------- Generic tiled fp32 GEMM: C = act(A @ W^T + bias) -------
// A: M x K (row stride lda), W: N x K row-major, C: M x N (row stride ldc)
// ACT: 0 none, 1 sigmoid, 2 softplus, 3 final (C = ep_x + acc*ep_g)
#define BM 64
#define BN 64
#define BK 16
template <int ACT>
__global__ __launch_bounds__(256) void gemm_k(
    const float* __restrict__ A, int lda, const float* __restrict__ W,
    const float* __restrict__ bias, float* __restrict__ C, int ldc, int M,
    int N, int K, const float* __restrict__ ep_x,
    const float* __restrict__ ep_g) {
  __shared__ float As[BM][BK + 1];
  __shared__ float Ws[BN][BK + 1];
  int tx = threadIdx.x & 15;
  int ty = threadIdx.x >> 4;
  int m0 = blockIdx.y * BM;
  int n0 = blockIdx.x * BN;
  float acc[4][4] = {};
  int r = threadIdx.x >> 2;        // 0..63
  int c4 = (threadIdx.x & 3) * 4;  // 0,4,8,12
  for (int k0 = 0; k0 < K; k0 += BK) {
    // load tiles (M is always a multiple of BM; K a multiple of BK)
    float4 av = *(const float4*)(A + (size_t)(m0 + r) * lda + k0 + c4);
    As[r][c4 + 0] = av.x; As[r][c4 + 1] = av.y;
    As[r][c4 + 2] = av.z; As[r][c4 + 3] = av.w;
    int n = n0 + r;
    float4 wv = make_float4(0.f, 0.f, 0.f, 0.f);
    if (n < N) wv = *(const float4*)(W + (size_t)n * K + k0 + c4);
    Ws[r][c4 + 0] = wv.x; Ws[r][c4 + 1] = wv.y;
    Ws[r][c4 + 2] = wv.z; Ws[r][c4 + 3] = wv.w;
    __syncthreads();
    #pragma unroll
    for (int k = 0; k < BK; ++k) {
      float a[4], bb[4];
      #pragma unroll
      for (int i = 0; i < 4; ++i) a[i] = As[ty * 4 + i][k];
      #pragma unroll
      for (int j = 0; j < 4; ++j) bb[j] = Ws[tx * 4 + j][k];
      #pragma unroll
      for (int i = 0; i < 4; ++i)
        #pragma unroll
        for (int j = 0; j < 4; ++j) acc[i][j] = fmaf(a[i], bb[j], acc[i][j]);
    }
    __syncthreads();
  }
  #pragma unroll
  for (int i = 0; i < 4; ++i) {
    int m = m0 + ty * 4 + i;
    #pragma unroll
    for (int j = 0; j < 4; ++j) {
      int n = n0 + tx * 4 + j;
      if (n < N) {
        float v = acc[i][j];
        if (bias) v += bias[n];
        if (ACT == 1) v = 1.f / (1.f + __expf(-v));
        if (ACT == 2) v = (v > 20.f) ? v : log1pf(__expf(v));
        size_t idx = (size_t)m * ldc + n;
        if (ACT == 3) v = ep_x[idx] + v * ep_g[idx];
        C[idx] = v;
      }
    }
  }
}

// ---------------- depthwise causal conv (k=4) + SiLU ----------------
__global__ __launch_bounds__(256) void conv_silu_k(
    const float* __restrict__ xz, const float* __restrict__ cw,
    const float* __restrict__ cb, float* __restrict__ u) {
  int idx = blockIdx.x * 256 + threadIdx.x;  // over B*L*DIN
  if (idx >= B_ * L_ * DIN_) return;
  int d = idx & (DIN_ - 1);
  int bl = idx >> 9;  // b*L + l
  int l = bl & (L_ - 1);
  float acc = cb[d];
  #pragma unroll
  for (int k = 0; k < DCONV_; ++k) {
    int ll = l - 3 + k;
    if (ll >= 0)
      acc = fmaf(xz[((size_t)(bl - l + ll)) * (2 * DIN_) + d], cw[d * 4 + k],
                 acc);
  }
  u[idx] = acc / (1.f + __expf(-acc));  // silu
}

// ---------------- selective scan ----------------
// one 64-lane wave handles 4 channels x 16 states for one batch b.
__global__ __launch_bounds__(256) void scan_k(
    const float* __restrict__ delta, const float* __restrict__ u,
    const float* __restrict__ xdbl, const float* __restrict__ xz,
    const float* __restrict__ A_log, const float* __restrict__ Dv,
    float* __restrict__ y) {
  int wave = (blockIdx.x << 2) + (threadIdx.x >> 6);  // 0..511
  int b = wave >> 7;    // 0..3
  int d4 = wave & 127;  // channel group
  int lane = threadIdx.x & 63;
  int s = lane & 15;
  int d = (d4 << 2) + (lane >> 4);
  float Ads = -__expf(A_log[d * DST_ + s]);
  float Dd = Dv[d];
  float h = 0.f;
  const float* dp = delta + (size_t)b * L_ * DIN_ + d;
  const float* up = u + (size_t)b * L_ * DIN_ + d;
  const float* bp = xdbl + (size_t)b * L_ * 48 + DTR_ + s;
  const float* cp = bp + DST_;
  const float* zp = xz + (size_t)b * L_ * (2 * DIN_) + DIN_ + d;
  float* yp = y + (size_t)b * L_ * DIN_ + d;
  for (int l = 0; l < L_; ++l) {
    float dl = dp[(size_t)l * DIN_];
    float ul = up[(size_t)l * DIN_];
    float Bs = bp[(size_t)l * 48];
    float Cs = cp[(size_t)l * 48];
    float dA = __expf(dl * Ads);
    h = fmaf(dA, h, dl * Bs * ul);
    float py = h * Cs;
    py += __shfl_xor(py, 8);
    py += __shfl_xor(py, 4);
    py += __shfl_xor(py, 2);
    py += __shfl_xor(py, 1);
    if (s == 0) {
      float z = zp[(size_t)l * (2 * DIN_)];
      float sil = z / (1.f + __expf(-z));
      yp[(size_t)l * DIN_] = (py + Dd * ul) * sil;
    }
  }
}

extern "C" void kernel_launch(void* const* d_in, const int* in_sizes, int n_in,
                              void* d_out, int out_size, void* d_ws,
                              size_t ws_size, hipStream_t stream) {
  const float* x = (const float*)d_in[0];
  const float* ln_g = (const float*)d_in[1];
  const float* ln_b = (const float*)d_in[2];
  const float* in_proj_w = (const float*)d_in[3];
  const float* conv_w = (const float*)d_in[4];
  const float* conv_b = (const float*)d_in[5];
  const float* x_proj_w = (const float*)d_in[6];
  const float* dt_proj_w = (const float*)d_in[7];
  const float* dt_proj_b = (const float*)d_in[8];
  const float* A_log = (const float*)d_in[9];
  const float* Dv = (const float*)d_in[10];
  const float* out_proj_w = (const float*)d_in[11];
  const float* gate_w = (const float*)d_in[12];
  const float* gate_b = (const float*)d_in[13];
  float* out = (float*)d_out;

  const int M = B_ * L_;  // 8192
  float* ws = (float*)d_ws;
  float* x_norm = ws;                      // 2,097,152
  float* xz = x_norm + (size_t)M * DIM_;   // 8,388,608
  float* u = xz + (size_t)M * 2 * DIN_;    // 4,194,304
  float* xdbl = u + (size_t)M * DIN_;      // 393,216
  float* delta = xdbl + (size_t)M * 48;    // 4,194,304
  float* y = delta + (size_t)M * DIN_;     // 4,194,304
  float* gate = y + (size_t)M * DIN_;      // 2,097,152

  // 1. LayerNorm
  ln_k<<<M, 256, 0, stream>>>(x, ln_g, ln_b, x_norm);
  // 2. in_proj: xz = x_norm @ in_proj_w^T   (M x 1024, K=256)
  gemm_k<0><<<dim3((2 * DIN_) / BN, M / BM), 256, 0, stream>>>(
      x_norm, DIM_, in_proj_w, nullptr, xz, 2 * DIN_, M, 2 * DIN_, DIM_,
      nullptr, nullptr);
  // 3. conv + silu -> u
  conv_silu_k<<<(M * DIN_ + 255) / 256, 256, 0, stream>>>(xz, conv_w, conv_b,
                                                          u);
  // 4. x_proj: xdbl = u @ x_proj_w^T   (M x 48, K=512)
  gemm_k<0><<<dim3(1, M / BM), 256, 0, stream>>>(u, DIN_, x_proj_w, nullptr,
                                                 xdbl, 48, M, 48, DIN_,
                                                 nullptr, nullptr);
  // 5. dt_proj: delta = softplus(xdbl[:, :16] @ dt_proj_w^T + b)  (M x 512, K=16)
  gemm_k<2><<<dim3(DIN_ / BN, M / BM), 256, 0, stream>>>(
      xdbl, 48, dt_proj_w, dt_proj_b, delta, DIN_, M, DIN_, DTR_, nullptr,
      nullptr);
  // 6. selective scan (+ D*u + silu(z) gating) -> y
  scan_k<<<128, 256, 0, stream>>>(delta, u, xdbl, xz, A_log, Dv, y);
  // 7. gate = sigmoid(x_norm @ gate_w^T + gate_b)  (M x 256, K=256)
  gemm_k<1><<<dim3(DIM_ / BN, M / BM), 256, 0, stream>>>(
      x_norm, DIM_, gate_w, gate_b, gate, DIM_, M, DIM_, DIM_, nullptr,
      nullptr);
  // 8. out = x + (y @ out_proj_w^T) * gate  (M x 256, K=512)
  gemm_k<3><<<dim3(DIM_ / BN, M / BM), 256, 0, stream>>>(
      y, DIN_, out_proj_w, nullptr, out, DIM_, M, DIM_, DIN_, x, gate);
}

// Round 2
// 502.496 us; speedup vs baseline: 3.7649x; 3.7649x over previous
//
#include <hip/hip_runtime.h>
#include <hip/hip_bf16.h>
#include <math.h>

#define B_ 4
#define L_ 2048
#define DIM_ 256
#define DST_ 16
#define DCONV_ 4
#define DIN_ 512   // D_INNER
#define DTR_ 16    // DT_RANK
#define CHUNK_ 64
#define NC_ (L_ / CHUNK_)  // 32

// ---------------- LayerNorm: one block (256 thr) per row ----------------
__global__ __launch_bounds__(256) void ln_k(const float* __restrict__ x,
                                            const float* __restrict__ g,
                                            const float* __restrict__ b,
                                            float* __restrict__ out) {
  int row = blockIdx.x;
  int t = threadIdx.x;
  float v = x[(size_t)row * DIM_ + t];
  float s = v, s2 = v * v;
  #pragma unroll
  for (int off = 32; off; off >>= 1) {
    s += __shfl_down(s, off);
    s2 += __shfl_down(s2, off);
  }
  __shared__ float ss[4], ss2[4];
  int w = t >> 6;
  if ((t & 63) == 0) { ss[w] = s; ss2[w] = s2; }
  __syncthreads();
  if (t == 0) {
    float S = ss[0] + ss[1] + ss[2] + ss[3];
    float S2 = ss2[0] + ss2[1] + ss2[2] + ss2[3];
    float mu = S * (1.f / DIM_);
    float var = S2 * (1.f / DIM_) - mu * mu;
    ss[0] = mu;
    ss2[0] = rsqrtf(var + 1e-5f);
  }
  __syncthreads();
  float mu = ss[0], rs = ss2[0];
  out[(size_t)row * DIM_ + t] = (v - mu) * rs * g[t] + b[t];
}

// ---------------- Generic tiled fp32 GEMM: C = act(A @ W^T + bias) -------
// A: M x K (row stride lda), W: N x K row-major, C: M x N (row stride ldc)
// ACT: 0 none, 1 sigmoid, 2 softplus, 3 final (C = ep_x + acc*ep_g)
#define BM 64
#define BN 64
#define BK 16
template <int ACT>
__global__ __launch_bounds__(256) void gemm_k(
    const float* __restrict__ A, int lda, const float* __restrict__ W,
    const float* __restrict__ bias, float* __restrict__ C, int ldc, int M,
    int N, int K, const float* __restrict__ ep_x,
    const float* __restrict__ ep_g) {
  __shared__ float As[BM][BK + 1];
  __shared__ float Ws[BN][BK + 1];
  int tx = threadIdx.x & 15;
  int ty = threadIdx.x >> 4;
  int m0 = blockIdx.y * BM;
  int n0 = blockIdx.x * BN;
  float acc[4][4] = {};
  int r = threadIdx.x >> 2;        // 0..63
  int c4 = (threadIdx.x & 3) * 4;  // 0,4,8,12
  for (int k0 = 0; k0 < K; k0 += BK) {
    float4 av = *(const float4*)(A + (size_t)(m0 + r) * lda + k0 + c4);
    As[r][c4 + 0] = av.x; As[r][c4 + 1] = av.y;
    As[r][c4 + 2] = av.z; As[r][c4 + 3] = av.w;
    int n = n0 + r;
    float4 wv = make_float4(0.f, 0.f, 0.f, 0.f);
    if (n < N) wv = *(const float4*)(W + (size_t)n * K + k0 + c4);
    Ws[r][c4 + 0] = wv.x; Ws[r][c4 + 1] = wv.y;
    Ws[r][c4 + 2] = wv.z; Ws[r][c4 + 3] = wv.w;
    __syncthreads();
    #pragma unroll
    for (int k = 0; k < BK; ++k) {
      float a[4], bb[4];
      #pragma unroll
      for (int i = 0; i < 4; ++i) a[i] = As[ty * 4 + i][k];
      #pragma unroll
      for (int j = 0; j < 4; ++j) bb[j] = Ws[tx * 4 + j][k];
      #pragma unroll
      for (int i = 0; i < 4; ++i)
        #pragma unroll
        for (int j = 0; j < 4; ++j) acc[i][j] = fmaf(a[i], bb[j], acc[i][j]);
    }
    __syncthreads();
  }
  #pragma unroll
  for (int i = 0; i < 4; ++i) {
    int m = m0 + ty * 4 + i;
    #pragma unroll
    for (int j = 0; j < 4; ++j) {
      int n = n0 + tx * 4 + j;
      if (n < N) {
        float v = acc[i][j];
        if (bias) v += bias[n];
        if (ACT == 1) v = 1.f / (1.f + __expf(-v));
        if (ACT == 2) v = (v > 20.f) ? v : log1pf(__expf(v));
        size_t idx = (size_t)m * ldc + n;
        if (ACT == 3) v = ep_x[idx] + v * ep_g[idx];
        C[idx] = v;
      }
    }
  }
}

// ---------------- depthwise causal conv (k=4) + SiLU ----------------
__global__ __launch_bounds__(256) void conv_silu_k(
    const float* __restrict__ xz, const float* __restrict__ cw,
    const float* __restrict__ cb, float* __restrict__ u) {
  int idx = blockIdx.x * 256 + threadIdx.x;  // over B*L*DIN
  if (idx >= B_ * L_ * DIN_) return;
  int d = idx & (DIN_ - 1);
  int bl = idx >> 9;  // b*L + l
  int l = bl & (L_ - 1);
  float acc = cb[d];
  #pragma unroll
  for (int k = 0; k < DCONV_; ++k) {
    int ll = l - 3 + k;
    if (ll >= 0)
      acc = fmaf(xz[((size_t)(bl - l + ll)) * (2 * DIN_) + d], cw[d * 4 + k],
                 acc);
  }
  u[idx] = acc / (1.f + __expf(-acc));  // silu
}

// ---------------- chunked selective scan ----------------
// wave mapping: wave = b*NC*128 + c*128 + g; lane: s = lane&15, d = g*4 + lane>>4

// phase 1: local scan from h=0; emit chunk-final h and cumulative dA product
__global__ __launch_bounds__(256) void scan_p1(
    const float* __restrict__ delta, const float* __restrict__ u,
    const float* __restrict__ xdbl, const float* __restrict__ A_log,
    float* __restrict__ hf, float* __restrict__ Pf) {
  int wave = (blockIdx.x << 2) + (threadIdx.x >> 6);
  int b = wave >> 12;
  int rest = wave & 4095;
  int c = rest >> 7;
  int g = rest & 127;
  int lane = threadIdx.x & 63;
  int s = lane & 15;
  int d = (g << 2) + (lane >> 4);
  float Ads = -__expf(A_log[d * DST_ + s]);
  float h = 0.f, Pp = 1.f;
  int l0 = c * CHUNK_;
  const float* dp = delta + ((size_t)b * L_ + l0) * DIN_ + d;
  const float* up = u + ((size_t)b * L_ + l0) * DIN_ + d;
  const float* bp = xdbl + ((size_t)b * L_ + l0) * 48 + DTR_ + s;
  #pragma unroll 8
  for (int l = 0; l < CHUNK_; ++l) {
    float dl = dp[(size_t)l * DIN_];
    float ul = up[(size_t)l * DIN_];
    float Bs = bp[(size_t)l * 48];
    float dA = __expf(dl * Ads);
    h = fmaf(dA, h, dl * Bs * ul);
    Pp *= dA;
  }
  size_t idx = (((size_t)b * NC_ + c) * DIN_ + d) * DST_ + s;
  hf[idx] = h;
  Pf[idx] = Pp;
}

// phase 2: serial combine across chunks -> per-chunk initial state h0
__global__ __launch_bounds__(256) void scan_p2(const float* __restrict__ hf,
                                               const float* __restrict__ Pf,
                                               float* __restrict__ h0) {
  int t = blockIdx.x * 256 + threadIdx.x;  // 0 .. B*DIN*DST-1 (32768)
  int b = t >> 13;
  int ds = t & 8191;
  float h = 0.f;
  #pragma unroll
  for (int c = 0; c < NC_; ++c) {
    size_t idx = (((size_t)b * NC_ + c) << 13) + ds;
    h0[idx] = h;
    h = fmaf(Pf[idx], h, hf[idx]);
  }
}

// phase 3: re-scan each chunk from true h0, write gated y
__global__ __launch_bounds__(256) void scan_p3(
    const float* __restrict__ delta, const float* __restrict__ u,
    const float* __restrict__ xdbl, const float* __restrict__ xz,
    const float* __restrict__ A_log, const float* __restrict__ Dv,
    const float* __restrict__ h0, float* __restrict__ y) {
  int wave = (blockIdx.x << 2) + (threadIdx.x >> 6);
  int b = wave >> 12;
  int rest = wave & 4095;
  int c = rest >> 7;
  int g = rest & 127;
  int lane = threadIdx.x & 63;
  int s = lane & 15;
  int d = (g << 2) + (lane >> 4);
  float Ads = -__expf(A_log[d * DST_ + s]);
  float Dd = Dv[d];
  size_t sidx = (((size_t)b * NC_ + c) * DIN_ + d) * DST_ + s;
  float h = h0[sidx];
  int l0 = c * CHUNK_;
  const float* dp = delta + ((size_t)b * L_ + l0) * DIN_ + d;
  const float* up = u + ((size_t)b * L_ + l0) * DIN_ + d;
  const float* bp = xdbl + ((size_t)b * L_ + l0) * 48 + DTR_ + s;
  const float* cp = bp + DST_;
  const float* zp = xz + ((size_t)b * L_ + l0) * (2 * DIN_) + DIN_ + d;
  float* yp = y + ((size_t)b * L_ + l0) * DIN_ + d;
  #pragma unroll 4
  for (int l = 0; l < CHUNK_; ++l) {
    float dl = dp[(size_t)l * DIN_];
    float ul = up[(size_t)l * DIN_];
    float Bs = bp[(size_t)l * 48];
    float Cs = cp[(size_t)l * 48];
    float dA = __expf(dl * Ads);
    h = fmaf(dA, h, dl * Bs * ul);
    float py = h * Cs;
    py += __shfl_xor(py, 8);
    py += __shfl_xor(py, 4);
    py += __shfl_xor(py, 2);
    py += __shfl_xor(py, 1);
    if (s == 0) {
      float z = zp[(size_t)l * (2 * DIN_)];
      float sil = z / (1.f + __expf(-z));
      yp[(size_t)l * DIN_] = (py + Dd * ul) * sil;
    }
  }
}

extern "C" void kernel_launch(void* const* d_in, const int* in_sizes, int n_in,
                              void* d_out, int out_size, void* d_ws,
                              size_t ws_size, hipStream_t stream) {
  const float* x = (const float*)d_in[0];
  const float* ln_g = (const float*)d_in[1];
  const float* ln_b = (const float*)d_in[2];
  const float* in_proj_w = (const float*)d_in[3];
  const float* conv_w = (const float*)d_in[4];
  const float* conv_b = (const float*)d_in[5];
  const float* x_proj_w = (const float*)d_in[6];
  const float* dt_proj_w = (const float*)d_in[7];
  const float* dt_proj_b = (const float*)d_in[8];
  const float* A_log = (const float*)d_in[9];
  const float* Dv = (const float*)d_in[10];
  const float* out_proj_w = (const float*)d_in[11];
  const float* gate_w = (const float*)d_in[12];
  const float* gate_b = (const float*)d_in[13];
  float* out = (float*)d_out;

  const int M = B_ * L_;  // 8192
  float* ws = (float*)d_ws;
  float* x_norm = ws;                      // 2,097,152
  float* xz = x_norm + (size_t)M * DIM_;   // 8,388,608
  float* u = xz + (size_t)M * 2 * DIN_;    // 4,194,304
  float* xdbl = u + (size_t)M * DIN_;      // 393,216
  float* delta = xdbl + (size_t)M * 48;    // 4,194,304
  float* y = delta + (size_t)M * DIN_;     // 4,194,304
  float* gate = y + (size_t)M * DIN_;      // 2,097,152
  float* hf = gate + (size_t)M * DIM_;     // 1,048,576
  float* Pf = hf + (size_t)B_ * NC_ * DIN_ * DST_;
  float* h0 = Pf + (size_t)B_ * NC_ * DIN_ * DST_;

  // 1. LayerNorm
  ln_k<<<M, 256, 0, stream>>>(x, ln_g, ln_b, x_norm);
  // 2. in_proj: xz = x_norm @ in_proj_w^T   (M x 1024, K=256)
  gemm_k<0><<<dim3((2 * DIN_) / BN, M / BM), 256, 0, stream>>>(
      x_norm, DIM_, in_proj_w, nullptr, xz, 2 * DIN_, M, 2 * DIN_, DIM_,
      nullptr, nullptr);
  // 3. conv + silu -> u
  conv_silu_k<<<(M * DIN_ + 255) / 256, 256, 0, stream>>>(xz, conv_w, conv_b,
                                                          u);
  // 4. x_proj: xdbl = u @ x_proj_w^T   (M x 48, K=512)
  gemm_k<0><<<dim3(1, M / BM), 256, 0, stream>>>(u, DIN_, x_proj_w, nullptr,
                                                 xdbl, 48, M, 48, DIN_,
                                                 nullptr, nullptr);
  // 5. dt_proj: delta = softplus(xdbl[:, :16] @ dt_proj_w^T + b)  (M x 512, K=16)
  gemm_k<2><<<dim3(DIN_ / BN, M / BM), 256, 0, stream>>>(
      xdbl, 48, dt_proj_w, dt_proj_b, delta, DIN_, M, DIN_, DTR_, nullptr,
      nullptr);
  // 6. chunked selective scan (+ D*u + silu(z) gating) -> y
  scan_p1<<<B_ * NC_ * 128 / 4, 256, 0, stream>>>(delta, u, xdbl, A_log, hf,
                                                  Pf);
  scan_p2<<<B_ * DIN_ * DST_ / 256, 256, 0, stream>>>(hf, Pf, h0);
  scan_p3<<<B_ * NC_ * 128 / 4, 256, 0, stream>>>(delta, u, xdbl, xz, A_log,
                                                  Dv, h0, y);
  // 7. gate = sigmoid(x_norm @ gate_w^T + gate_b)  (M x 256, K=256)
  gemm_k<1><<<dim3(DIM_ / BN, M / BM), 256, 0, stream>>>(
      x_norm, DIM_, gate_w, gate_b, gate, DIM_, M, DIM_, DIM_, nullptr,
      nullptr);
  // 8. out = x + (y @ out_proj_w^T) * gate  (M x 256, K=512)
  gemm_k<3><<<dim3(DIM_ / BN, M / BM), 256, 0, stream>>>(
      y, DIN_, out_proj_w, nullptr, out, DIM_, M, DIM_, DIN_, x, gate);
}

// Round 3
// 373.595 us; speedup vs baseline: 5.0639x; 1.3450x over previous
//
#include <hip/hip_runtime.h>
#include <hip/hip_bf16.h>
#include <math.h>

#define B_ 4
#define L_ 2048
#define DIM_ 256
#define DST_ 16
#define DCONV_ 4
#define DIN_ 512   // D_INNER
#define DTR_ 16    // DT_RANK
#define CHUNK_ 64
#define NC_ (L_ / CHUNK_)  // 32

typedef __attribute__((ext_vector_type(8))) short short8;
typedef __attribute__((ext_vector_type(4))) float floatx4;
typedef __hip_bfloat16 bf16;

// ---------------- weight fp32 -> bf16 conversion (5 tensors) ----------------
__global__ __launch_bounds__(256) void wcvt_k(
    const float* __restrict__ s0, const float* __restrict__ s1,
    const float* __restrict__ s2, const float* __restrict__ s3,
    const float* __restrict__ s4, bf16* __restrict__ d0, bf16* __restrict__ d1,
    bf16* __restrict__ d2, bf16* __restrict__ d3, bf16* __restrict__ d4) {
  int i = blockIdx.x * 256 + threadIdx.x;
  if (i < 262144) d0[i] = __float2bfloat16(s0[i]);  // in_proj_w 1024x256
  if (i < 24576) d1[i] = __float2bfloat16(s1[i]);   // x_proj_w  48x512
  if (i < 8192) d2[i] = __float2bfloat16(s2[i]);    // dt_proj_w 512x16
  if (i < 131072) d3[i] = __float2bfloat16(s3[i]);  // out_proj_w 256x512
  if (i < 65536) d4[i] = __float2bfloat16(s4[i]);   // gate_w   256x256
}

// ---------------- LayerNorm: one block (256 thr) per row, bf16 out ---------
__global__ __launch_bounds__(256) void ln_k(const float* __restrict__ x,
                                            const float* __restrict__ g,
                                            const float* __restrict__ b,
                                            bf16* __restrict__ out) {
  int row = blockIdx.x;
  int t = threadIdx.x;
  float v = x[(size_t)row * DIM_ + t];
  float s = v, s2 = v * v;
  #pragma unroll
  for (int off = 32; off; off >>= 1) {
    s += __shfl_down(s, off);
    s2 += __shfl_down(s2, off);
  }
  __shared__ float ss[4], ss2[4];
  int w = t >> 6;
  if ((t & 63) == 0) { ss[w] = s; ss2[w] = s2; }
  __syncthreads();
  if (t == 0) {
    float S = ss[0] + ss[1] + ss[2] + ss[3];
    float S2 = ss2[0] + ss2[1] + ss2[2] + ss2[3];
    float mu = S * (1.f / DIM_);
    float var = S2 * (1.f / DIM_) - mu * mu;
    ss[0] = mu;
    ss2[0] = rsqrtf(var + 1e-5f);
  }
  __syncthreads();
  float mu = ss[0], rs = ss2[0];
  out[(size_t)row * DIM_ + t] = __float2bfloat16((v - mu) * rs * g[t] + b[t]);
}

// ---------------- bf16 MFMA GEMM: C = act(A @ W^T + bias) ------------------
// A: M x K bf16 (row stride lda, K-contiguous). W: N x K bf16 row-major.
// 16x16x32 MFMA, fragments loaded straight from global (L1/L2-cached reuse).
// A-frag: lane holds A[m0+lane&15][k0+(lane>>4)*8 + 0..7]
// B-frag: lane holds W[n0+lane&15][k0+(lane>>4)*8 + 0..7]
// D:      col(n) = lane&15, row(m) = (lane>>4)*4 + reg        [m89/m91]
// ACT: 0 none(bf16 out), 1 sigmoid(f32 out), 2 softplus(bf16 out),
//      3 final: f32 out = ep_x + acc*ep_g
template <int BMW, int BNW, int WMT, int WNT, int ACT>
__global__ __launch_bounds__(256) void mgemm_k(
    const bf16* __restrict__ A, int lda, const bf16* __restrict__ W,
    const float* __restrict__ bias, void* __restrict__ Cp, int ldc, int M,
    int N, int K, const float* __restrict__ ep_x,
    const float* __restrict__ ep_g) {
  constexpr int BM = BMW * WMT * 16;
  constexpr int BN = BNW * WNT * 16;
  int wave = threadIdx.x >> 6;
  int lane = threadIdx.x & 63;
  int wm = wave / BNW, wn = wave % BNW;
  int m_base = blockIdx.y * BM + wm * (WMT * 16);
  int n_base = blockIdx.x * BN + wn * (WNT * 16);
  int lr = lane & 15;    // m (A) / n (W) / col (D)
  int quad = lane >> 4;  // k-octet select / D row-quad
  const short8 zz = {0, 0, 0, 0, 0, 0, 0, 0};
  floatx4 acc[WMT][WNT];
  #pragma unroll
  for (int i = 0; i < WMT; ++i)
    #pragma unroll
    for (int j = 0; j < WNT; ++j) acc[i][j] = (floatx4){0.f, 0.f, 0.f, 0.f};

  for (int k0 = 0; k0 < K; k0 += 32) {
    int kk = k0 + quad * 8;
    bool kin = (kk < K);  // K=16 case: quads 2,3 contribute zeros
    short8 a[WMT], b[WNT];
    #pragma unroll
    for (int i = 0; i < WMT; ++i) {
      const short* p = (const short*)A + (size_t)(m_base + i * 16 + lr) * lda + kk;
      a[i] = kin ? *(const short8*)p : zz;
    }
    #pragma unroll
    for (int j = 0; j < WNT; ++j) {
      int n = n_base + j * 16 + lr;
      const short* p = (const short*)W + (size_t)n * K + kk;
      b[j] = (kin && n < N) ? *(const short8*)p : zz;
    }
    #pragma unroll
    for (int i = 0; i < WMT; ++i)
      #pragma unroll
      for (int j = 0; j < WNT; ++j)
        acc[i][j] =
            __builtin_amdgcn_mfma_f32_16x16x32_bf16(a[i], b[j], acc[i][j], 0, 0, 0);
  }

  #pragma unroll
  for (int i = 0; i < WMT; ++i) {
    int m = m_base + i * 16 + quad * 4;
    #pragma unroll
    for (int j = 0; j < WNT; ++j) {
      int n = n_base + j * 16 + lr;
      if (n < N) {
        #pragma unroll
        for (int r = 0; r < 4; ++r) {
          float v = acc[i][j][r];
          if (bias) v += bias[n];
          if (ACT == 1) v = 1.f / (1.f + __expf(-v));
          if (ACT == 2) v = (v > 20.f) ? v : log1pf(__expf(v));
          size_t idx = (size_t)(m + r) * ldc + n;
          if (ACT == 1) {
            ((float*)Cp)[idx] = v;
          } else if (ACT == 3) {
            ((float*)Cp)[idx] = ep_x[idx] + v * ep_g[idx];
          } else {
            ((bf16*)Cp)[idx] = __float2bfloat16(v);
          }
        }
      }
    }
  }
}

// ---------------- depthwise causal conv (k=4) + SiLU, bf16 io --------------
__global__ __launch_bounds__(256) void conv_silu_k(
    const bf16* __restrict__ xz, const float* __restrict__ cw,
    const float* __restrict__ cb, bf16* __restrict__ u) {
  int idx = blockIdx.x * 256 + threadIdx.x;  // over B*L*DIN
  if (idx >= B_ * L_ * DIN_) return;
  int d = idx & (DIN_ - 1);
  int bl = idx >> 9;  // b*L + l
  int l = bl & (L_ - 1);
  float acc = cb[d];
  #pragma unroll
  for (int k = 0; k < DCONV_; ++k) {
    int ll = l - 3 + k;
    if (ll >= 0)
      acc = fmaf(__bfloat162float(xz[((size_t)(bl - l + ll)) * (2 * DIN_) + d]),
                 cw[d * 4 + k], acc);
  }
  u[idx] = __float2bfloat16(acc / (1.f + __expf(-acc)));  // silu
}

// ---------------- chunked selective scan (bf16 activations) ----------------
// wave: b, chunk c, channel group g (4 ch); lane: s=lane&15, d=g*4+lane>>4

__global__ __launch_bounds__(256) void scan_p1(
    const bf16* __restrict__ delta, const bf16* __restrict__ u,
    const bf16* __restrict__ xdbl, const float* __restrict__ A_log,
    float* __restrict__ hf, float* __restrict__ Pf) {
  int wave = (blockIdx.x << 2) + (threadIdx.x >> 6);
  int b = wave >> 12;
  int rest = wave & 4095;
  int c = rest >> 7;
  int g = rest & 127;
  int lane = threadIdx.x & 63;
  int s = lane & 15;
  int d = (g << 2) + (lane >> 4);
  float Ads = -__expf(A_log[d * DST_ + s]);
  float h = 0.f, Pp = 1.f;
  int l0 = c * CHUNK_;
  const bf16* dp = delta + ((size_t)b * L_ + l0) * DIN_ + d;
  const bf16* up = u + ((size_t)b * L_ + l0) * DIN_ + d;
  const bf16* bp = xdbl + ((size_t)b * L_ + l0) * 48 + DTR_ + s;
  #pragma unroll 8
  for (int l = 0; l < CHUNK_; ++l) {
    float dl = __bfloat162float(dp[(size_t)l * DIN_]);
    float ul = __bfloat162float(up[(size_t)l * DIN_]);
    float Bs = __bfloat162float(bp[(size_t)l * 48]);
    float dA = __expf(dl * Ads);
    h = fmaf(dA, h, dl * Bs * ul);
    Pp *= dA;
  }
  size_t idx = (((size_t)b * NC_ + c) * DIN_ + d) * DST_ + s;
  hf[idx] = h;
  Pf[idx] = Pp;
}

__global__ __launch_bounds__(256) void scan_p2(const float* __restrict__ hf,
                                               const float* __restrict__ Pf,
                                               float* __restrict__ h0) {
  int t = blockIdx.x * 256 + threadIdx.x;  // 0 .. B*DIN*DST-1 (32768)
  int b = t >> 13;
  int ds = t & 8191;
  float h = 0.f;
  #pragma unroll
  for (int c = 0; c < NC_; ++c) {
    size_t idx = (((size_t)b * NC_ + c) << 13) + ds;
    h0[idx] = h;
    h = fmaf(Pf[idx], h, hf[idx]);
  }
}

__global__ __launch_bounds__(256) void scan_p3(
    const bf16* __restrict__ delta, const bf16* __restrict__ u,
    const bf16* __restrict__ xdbl, const bf16* __restrict__ xz,
    const float* __restrict__ A_log, const float* __restrict__ Dv,
    const float* __restrict__ h0, bf16* __restrict__ y) {
  int wave = (blockIdx.x << 2) + (threadIdx.x >> 6);
  int b = wave >> 12;
  int rest = wave & 4095;
  int c = rest >> 7;
  int g = rest & 127;
  int lane = threadIdx.x & 63;
  int s = lane & 15;
  int d = (g << 2) + (lane >> 4);
  float Ads = -__expf(A_log[d * DST_ + s]);
  float Dd = Dv[d];
  size_t sidx = (((size_t)b * NC_ + c) * DIN_ + d) * DST_ + s;
  float h = h0[sidx];
  int l0 = c * CHUNK_;
  const bf16* dp = delta + ((size_t)b * L_ + l0) * DIN_ + d;
  const bf16* up = u + ((size_t)b * L_ + l0) * DIN_ + d;
  const bf16* bp = xdbl + ((size_t)b * L_ + l0) * 48 + DTR_ + s;
  const bf16* cp = bp + DST_;
  const bf16* zp = xz + ((size_t)b * L_ + l0) * (2 * DIN_) + DIN_ + d;
  bf16* yp = y + ((size_t)b * L_ + l0) * DIN_ + d;
  #pragma unroll 4
  for (int l = 0; l < CHUNK_; ++l) {
    float dl = __bfloat162float(dp[(size_t)l * DIN_]);
    float ul = __bfloat162float(up[(size_t)l * DIN_]);
    float Bs = __bfloat162float(bp[(size_t)l * 48]);
    float Cs = __bfloat162float(cp[(size_t)l * 48]);
    float dA = __expf(dl * Ads);
    h = fmaf(dA, h, dl * Bs * ul);
    float py = h * Cs;
    py += __shfl_xor(py, 8);
    py += __shfl_xor(py, 4);
    py += __shfl_xor(py, 2);
    py += __shfl_xor(py, 1);
    if (s == 0) {
      float z = __bfloat162float(zp[(size_t)l * (2 * DIN_)]);
      float sil = z / (1.f + __expf(-z));
      yp[(size_t)l * DIN_] = __float2bfloat16((py + Dd * ul) * sil);
    }
  }
}

extern "C" void kernel_launch(void* const* d_in, const int* in_sizes, int n_in,
                              void* d_out, int out_size, void* d_ws,
                              size_t ws_size, hipStream_t stream) {
  const float* x = (const float*)d_in[0];
  const float* ln_g = (const float*)d_in[1];
  const float* ln_b = (const float*)d_in[2];
  const float* in_proj_w = (const float*)d_in[3];
  const float* conv_w = (const float*)d_in[4];
  const float* conv_b = (const float*)d_in[5];
  const float* x_proj_w = (const float*)d_in[6];
  const float* dt_proj_w = (const float*)d_in[7];
  const float* dt_proj_b = (const float*)d_in[8];
  const float* A_log = (const float*)d_in[9];
  const float* Dv = (const float*)d_in[10];
  const float* out_proj_w = (const float*)d_in[11];
  const float* gate_w = (const float*)d_in[12];
  const float* gate_b = (const float*)d_in[13];
  float* out = (float*)d_out;

  const int M = B_ * L_;  // 8192
  char* w = (char*)d_ws;
  auto alloc = [&](size_t bytes) {
    void* p = w;
    w += (bytes + 255) & ~(size_t)255;
    return p;
  };
  bf16* x_norm = (bf16*)alloc((size_t)M * DIM_ * 2);
  bf16* xz = (bf16*)alloc((size_t)M * 2 * DIN_ * 2);
  bf16* u = (bf16*)alloc((size_t)M * DIN_ * 2);
  bf16* xdbl = (bf16*)alloc((size_t)M * 48 * 2);
  bf16* delta = (bf16*)alloc((size_t)M * DIN_ * 2);
  bf16* y = (bf16*)alloc((size_t)M * DIN_ * 2);
  float* gate = (float*)alloc((size_t)M * DIM_ * 4);
  float* hf = (float*)alloc((size_t)B_ * NC_ * DIN_ * DST_ * 4);
  float* Pf = (float*)alloc((size_t)B_ * NC_ * DIN_ * DST_ * 4);
  float* h0 = (float*)alloc((size_t)B_ * NC_ * DIN_ * DST_ * 4);
  bf16* w_in = (bf16*)alloc(262144 * 2);
  bf16* w_xp = (bf16*)alloc(24576 * 2);
  bf16* w_dt = (bf16*)alloc(8192 * 2);
  bf16* w_op = (bf16*)alloc(131072 * 2);
  bf16* w_gt = (bf16*)alloc(65536 * 2);

  // 0. weights -> bf16
  wcvt_k<<<1024, 256, 0, stream>>>(in_proj_w, x_proj_w, dt_proj_w, out_proj_w,
                                   gate_w, w_in, w_xp, w_dt, w_op, w_gt);
  // 1. LayerNorm -> bf16
  ln_k<<<M, 256, 0, stream>>>(x, ln_g, ln_b, x_norm);
  // 2. in_proj: xz = x_norm @ in_proj_w^T   (M x 1024, K=256)
  mgemm_k<2, 2, 4, 4, 0><<<dim3(8, 64), 256, 0, stream>>>(
      x_norm, DIM_, w_in, nullptr, xz, 2 * DIN_, M, 2 * DIN_, DIM_, nullptr,
      nullptr);
  // 3. conv + silu -> u
  conv_silu_k<<<(M * DIN_ + 255) / 256, 256, 0, stream>>>(xz, conv_w, conv_b,
                                                          u);
  // 4. x_proj: xdbl = u @ x_proj_w^T   (M x 48, K=512)
  mgemm_k<4, 1, 1, 3, 0><<<dim3(1, 128), 256, 0, stream>>>(
      u, DIN_, w_xp, nullptr, xdbl, 48, M, 48, DIN_, nullptr, nullptr);
  // 5. dt_proj: delta = softplus(xdbl[:,:16] @ dt_proj_w^T + b)  (K=16 pad 32)
  mgemm_k<2, 2, 4, 4, 2><<<dim3(4, 64), 256, 0, stream>>>(
      xdbl, 48, w_dt, dt_proj_b, delta, DIN_, M, DIN_, DTR_, nullptr, nullptr);
  // 6. chunked selective scan (+ D*u + silu(z) gating) -> y
  scan_p1<<<B_ * NC_ * 128 / 4, 256, 0, stream>>>(delta, u, xdbl, A_log, hf,
                                                  Pf);
  scan_p2<<<B_ * DIN_ * DST_ / 256, 256, 0, stream>>>(hf, Pf, h0);
  scan_p3<<<B_ * NC_ * 128 / 4, 256, 0, stream>>>(delta, u, xdbl, xz, A_log,
                                                  Dv, h0, y);
  // 7. gate = sigmoid(x_norm @ gate_w^T + gate_b)  (M x 256, K=256)
  mgemm_k<2, 2, 4, 4, 1><<<dim3(2, 64), 256, 0, stream>>>(
      x_norm, DIM_, w_gt, gate_b, gate, DIM_, M, DIM_, DIM_, nullptr, nullptr);
  // 8. out = x + (y @ out_proj_w^T) * gate  (M x 256, K=512)
  mgemm_k<2, 2, 4, 4, 3><<<dim3(2, 64), 256, 0, stream>>>(
      y, DIN_, w_op, nullptr, out, DIM_, M, DIM_, DIN_, x, gate);
}

// Round 4
// 288.061 us; speedup vs baseline: 6.5676x; 1.2969x over previous
//
#include <hip/hip_runtime.h>
#include <hip/hip_bf16.h>
#include <math.h>

#define B_ 4
#define L_ 2048
#define DIM_ 256
#define DST_ 16
#define DCONV_ 4
#define DIN_ 512   // D_INNER
#define DTR_ 16    // DT_RANK
#define CHUNK_ 32
#define NC_ (L_ / CHUNK_)  // 64

typedef __attribute__((ext_vector_type(8))) short short8;
typedef __attribute__((ext_vector_type(4))) float floatx4;
typedef __hip_bfloat16 bf16;

// ---------------- weight fp32 -> bf16 conversion (5 tensors) ----------------
__global__ __launch_bounds__(256) void wcvt_k(
    const float* __restrict__ s0, const float* __restrict__ s1,
    const float* __restrict__ s2, const float* __restrict__ s3,
    const float* __restrict__ s4, bf16* __restrict__ d0, bf16* __restrict__ d1,
    bf16* __restrict__ d2, bf16* __restrict__ d3, bf16* __restrict__ d4) {
  int i = blockIdx.x * 256 + threadIdx.x;
  if (i < 262144) d0[i] = __float2bfloat16(s0[i]);  // in_proj_w 1024x256
  if (i < 24576) d1[i] = __float2bfloat16(s1[i]);   // x_proj_w  48x512
  if (i < 8192) d2[i] = __float2bfloat16(s2[i]);    // dt_proj_w 512x16
  if (i < 131072) d3[i] = __float2bfloat16(s3[i]);  // out_proj_w 256x512
  if (i < 65536) d4[i] = __float2bfloat16(s4[i]);   // gate_w   256x256
}

// ---------------- LayerNorm: one block (256 thr) per row, bf16 out ---------
__global__ __launch_bounds__(256) void ln_k(const float* __restrict__ x,
                                            const float* __restrict__ g,
                                            const float* __restrict__ b,
                                            bf16* __restrict__ out) {
  int row = blockIdx.x;
  int t = threadIdx.x;
  float v = x[(size_t)row * DIM_ + t];
  float s = v, s2 = v * v;
  #pragma unroll
  for (int off = 32; off; off >>= 1) {
    s += __shfl_down(s, off);
    s2 += __shfl_down(s2, off);
  }
  __shared__ float ss[4], ss2[4];
  int w = t >> 6;
  if ((t & 63) == 0) { ss[w] = s; ss2[w] = s2; }
  __syncthreads();
  if (t == 0) {
    float S = ss[0] + ss[1] + ss[2] + ss[3];
    float S2 = ss2[0] + ss2[1] + ss2[2] + ss2[3];
    float mu = S * (1.f / DIM_);
    float var = S2 * (1.f / DIM_) - mu * mu;
    ss[0] = mu;
    ss2[0] = rsqrtf(var + 1e-5f);
  }
  __syncthreads();
  float mu = ss[0], rs = ss2[0];
  out[(size_t)row * DIM_ + t] = __float2bfloat16((v - mu) * rs * g[t] + b[t]);
}

// ---------------- bf16 MFMA GEMM: C = act(A @ W^T + bias) ------------------
template <int BMW, int BNW, int WMT, int WNT, int ACT>
__global__ __launch_bounds__(256) void mgemm_k(
    const bf16* __restrict__ A, int lda, const bf16* __restrict__ W,
    const float* __restrict__ bias, void* __restrict__ Cp, int ldc, int M,
    int N, int K, const float* __restrict__ ep_x,
    const float* __restrict__ ep_g) {
  constexpr int BM = BMW * WMT * 16;
  constexpr int BN = BNW * WNT * 16;
  int wave = threadIdx.x >> 6;
  int lane = threadIdx.x & 63;
  int wm = wave / BNW, wn = wave % BNW;
  int m_base = blockIdx.y * BM + wm * (WMT * 16);
  int n_base = blockIdx.x * BN + wn * (WNT * 16);
  int lr = lane & 15;    // m (A) / n (W) / col (D)
  int quad = lane >> 4;  // k-octet select / D row-quad
  const short8 zz = {0, 0, 0, 0, 0, 0, 0, 0};
  floatx4 acc[WMT][WNT];
  #pragma unroll
  for (int i = 0; i < WMT; ++i)
    #pragma unroll
    for (int j = 0; j < WNT; ++j) acc[i][j] = (floatx4){0.f, 0.f, 0.f, 0.f};

  for (int k0 = 0; k0 < K; k0 += 32) {
    int kk = k0 + quad * 8;
    bool kin = (kk < K);  // K=16 case: quads 2,3 contribute zeros
    short8 a[WMT], b[WNT];
    #pragma unroll
    for (int i = 0; i < WMT; ++i) {
      const short* p = (const short*)A + (size_t)(m_base + i * 16 + lr) * lda + kk;
      a[i] = kin ? *(const short8*)p : zz;
    }
    #pragma unroll
    for (int j = 0; j < WNT; ++j) {
      int n = n_base + j * 16 + lr;
      const short* p = (const short*)W + (size_t)n * K + kk;
      b[j] = (kin && n < N) ? *(const short8*)p : zz;
    }
    #pragma unroll
    for (int i = 0; i < WMT; ++i)
      #pragma unroll
      for (int j = 0; j < WNT; ++j)
        acc[i][j] =
            __builtin_amdgcn_mfma_f32_16x16x32_bf16(a[i], b[j], acc[i][j], 0, 0, 0);
  }

  #pragma unroll
  for (int i = 0; i < WMT; ++i) {
    int m = m_base + i * 16 + quad * 4;
    #pragma unroll
    for (int j = 0; j < WNT; ++j) {
      int n = n_base + j * 16 + lr;
      if (n < N) {
        #pragma unroll
        for (int r = 0; r < 4; ++r) {
          float v = acc[i][j][r];
          if (bias) v += bias[n];
          if (ACT == 1) v = 1.f / (1.f + __expf(-v));
          if (ACT == 2) v = (v > 20.f) ? v : log1pf(__expf(v));
          size_t idx = (size_t)(m + r) * ldc + n;
          if (ACT == 1) {
            ((float*)Cp)[idx] = v;
          } else if (ACT == 3) {
            ((float*)Cp)[idx] = ep_x[idx] + v * ep_g[idx];
          } else {
            ((bf16*)Cp)[idx] = __float2bfloat16(v);
          }
        }
      }
    }
  }
}

// ---------------- depthwise causal conv (k=4) + SiLU, bf16 io --------------
__global__ __launch_bounds__(256) void conv_silu_k(
    const bf16* __restrict__ xz, const float* __restrict__ cw,
    const float* __restrict__ cb, bf16* __restrict__ u) {
  int idx = blockIdx.x * 256 + threadIdx.x;  // over B*L*DIN
  if (idx >= B_ * L_ * DIN_) return;
  int d = idx & (DIN_ - 1);
  int bl = idx >> 9;  // b*L + l
  int l = bl & (L_ - 1);
  float acc = cb[d];
  #pragma unroll
  for (int k = 0; k < DCONV_; ++k) {
    int ll = l - 3 + k;
    if (ll >= 0)
      acc = fmaf(__bfloat162float(xz[((size_t)(bl - l + ll)) * (2 * DIN_) + d]),
                 cw[d * 4 + k], acc);
  }
  u[idx] = __float2bfloat16(acc / (1.f + __expf(-acc)));  // silu
}

// ---------------- chunked selective scan, lane-per-channel -----------------
// block = 256 threads covers 256 channels of one (b, chunk); 2 blocks per
// (b,chunk). Each thread owns channel d with 16 states in VGPRs.
// blockIdx.x = b*(NC_*2) + c*2 + half

// phase 1: local scan from h=0; emit chunk-final h and dA-product
__global__ __launch_bounds__(256) void scan_p1(
    const bf16* __restrict__ delta, const bf16* __restrict__ u,
    const bf16* __restrict__ xdbl, const float* __restrict__ A_log,
    float* __restrict__ hf, float* __restrict__ Pf) {
  __shared__ float sB[CHUNK_][16];
  int blk = blockIdx.x;
  int half = blk & 1;
  int c = (blk >> 1) & (NC_ - 1);
  int b = blk >> 7;  // NC_*2 = 128
  int tid = threadIdx.x;
  int d = half * 256 + tid;
  size_t row0 = (size_t)b * L_ + c * CHUNK_;
  for (int idx = tid; idx < CHUNK_ * 16; idx += 256) {
    int l = idx >> 4, j = idx & 15;
    sB[l][j] = __bfloat162float(xdbl[(row0 + l) * 48 + DTR_ + j]);
  }
  __syncthreads();
  float Ads[16];
  #pragma unroll
  for (int s = 0; s < 16; ++s) Ads[s] = -__expf(A_log[d * DST_ + s]);
  float h[16];
  #pragma unroll
  for (int s = 0; s < 16; ++s) h[s] = 0.f;
  float cd = 0.f;
  const bf16* dp = delta + row0 * DIN_ + d;
  const bf16* up = u + row0 * DIN_ + d;
  for (int l = 0; l < CHUNK_; ++l) {
    float dl = __bfloat162float(dp[(size_t)l * DIN_]);
    float ul = __bfloat162float(up[(size_t)l * DIN_]);
    cd += dl;
    float dlul = dl * ul;
    float bb[16];
    const float4* Bv = (const float4*)&sB[l][0];
    *(float4*)&bb[0] = Bv[0];
    *(float4*)&bb[4] = Bv[1];
    *(float4*)&bb[8] = Bv[2];
    *(float4*)&bb[12] = Bv[3];
    #pragma unroll
    for (int s = 0; s < 16; ++s) {
      float dA = __expf(dl * Ads[s]);
      h[s] = fmaf(dA, h[s], bb[s] * dlul);
    }
  }
  size_t o = (((size_t)b * NC_ + c) * DIN_ + d) * DST_;
  #pragma unroll
  for (int s = 0; s < 16; ++s) {
    hf[o + s] = h[s];
    Pf[o + s] = __expf(cd * Ads[s]);  // == prod_l exp(dl*Ads)
  }
}

// phase 2: serial combine across chunks, IN-PLACE: hf becomes h0
__global__ __launch_bounds__(256) void scan_p2(float* __restrict__ hf,
                                               const float* __restrict__ Pf) {
  int t = blockIdx.x * 256 + threadIdx.x;  // 0 .. B*DIN*DST-1 (32768)
  int b = t >> 13;
  int ds = t & 8191;
  float h = 0.f;
  #pragma unroll 8
  for (int c = 0; c < NC_; ++c) {
    size_t idx = (((size_t)b * NC_ + c) << 13) + ds;
    float hfc = hf[idx];
    float p = Pf[idx];
    hf[idx] = h;  // h0 for chunk c
    h = fmaf(p, h, hfc);
  }
}

// phase 3: re-scan each chunk from h0 (in hf), write gated y (aliases delta)
__global__ __launch_bounds__(256) void scan_p3(
    const bf16* __restrict__ delta, const bf16* __restrict__ u,
    const bf16* __restrict__ xdbl, const bf16* __restrict__ xz,
    const float* __restrict__ A_log, const float* __restrict__ Dv,
    const float* __restrict__ h0, bf16* __restrict__ y) {
  __shared__ float sBC[CHUNK_][32];  // [l][0:16]=B, [l][16:32]=C
  int blk = blockIdx.x;
  int half = blk & 1;
  int c = (blk >> 1) & (NC_ - 1);
  int b = blk >> 7;
  int tid = threadIdx.x;
  int d = half * 256 + tid;
  size_t row0 = (size_t)b * L_ + c * CHUNK_;
  for (int idx = tid; idx < CHUNK_ * 32; idx += 256) {
    int l = idx >> 5, j = idx & 31;
    sBC[l][j] = __bfloat162float(xdbl[(row0 + l) * 48 + DTR_ + j]);
  }
  __syncthreads();
  float Ads[16];
  #pragma unroll
  for (int s = 0; s < 16; ++s) Ads[s] = -__expf(A_log[d * DST_ + s]);
  float Dd = Dv[d];
  size_t o = (((size_t)b * NC_ + c) * DIN_ + d) * DST_;
  float h[16];
  #pragma unroll
  for (int s = 0; s < 16; ++s) h[s] = h0[o + s];
  const bf16* dp = delta + row0 * DIN_ + d;
  const bf16* up = u + row0 * DIN_ + d;
  const bf16* zp = xz + row0 * (2 * DIN_) + DIN_ + d;
  bf16* yp = y + row0 * DIN_ + d;
  for (int l = 0; l < CHUNK_; ++l) {
    float dl = __bfloat162float(dp[(size_t)l * DIN_]);
    float ul = __bfloat162float(up[(size_t)l * DIN_]);
    float z = __bfloat162float(zp[(size_t)l * (2 * DIN_)]);
    float dlul = dl * ul;
    float bb[16], cc[16];
    const float4* Bv = (const float4*)&sBC[l][0];
    *(float4*)&bb[0] = Bv[0];
    *(float4*)&bb[4] = Bv[1];
    *(float4*)&bb[8] = Bv[2];
    *(float4*)&bb[12] = Bv[3];
    *(float4*)&cc[0] = Bv[4];
    *(float4*)&cc[4] = Bv[5];
    *(float4*)&cc[8] = Bv[6];
    *(float4*)&cc[12] = Bv[7];
    float py = 0.f;
    #pragma unroll
    for (int s = 0; s < 16; ++s) {
      float dA = __expf(dl * Ads[s]);
      h[s] = fmaf(dA, h[s], bb[s] * dlul);
      py = fmaf(h[s], cc[s], py);
    }
    float sil = z / (1.f + __expf(-z));
    yp[(size_t)l * DIN_] = __float2bfloat16((py + Dd * ul) * sil);
  }
}

extern "C" void kernel_launch(void* const* d_in, const int* in_sizes, int n_in,
                              void* d_out, int out_size, void* d_ws,
                              size_t ws_size, hipStream_t stream) {
  const float* x = (const float*)d_in[0];
  const float* ln_g = (const float*)d_in[1];
  const float* ln_b = (const float*)d_in[2];
  const float* in_proj_w = (const float*)d_in[3];
  const float* conv_w = (const float*)d_in[4];
  const float* conv_b = (const float*)d_in[5];
  const float* x_proj_w = (const float*)d_in[6];
  const float* dt_proj_w = (const float*)d_in[7];
  const float* dt_proj_b = (const float*)d_in[8];
  const float* A_log = (const float*)d_in[9];
  const float* Dv = (const float*)d_in[10];
  const float* out_proj_w = (const float*)d_in[11];
  const float* gate_w = (const float*)d_in[12];
  const float* gate_b = (const float*)d_in[13];
  float* out = (float*)d_out;

  const int M = B_ * L_;  // 8192
  char* w = (char*)d_ws;
  auto alloc = [&](size_t bytes) {
    void* p = w;
    w += (bytes + 255) & ~(size_t)255;
    return p;
  };
  bf16* x_norm = (bf16*)alloc((size_t)M * DIM_ * 2);
  bf16* xz = (bf16*)alloc((size_t)M * 2 * DIN_ * 2);
  bf16* u = (bf16*)alloc((size_t)M * DIN_ * 2);
  bf16* xdbl = (bf16*)alloc((size_t)M * 48 * 2);
  bf16* delta = (bf16*)alloc((size_t)M * DIN_ * 2);  // y aliases this in p3
  float* gate = (float*)alloc((size_t)M * DIM_ * 4);
  float* hf = (float*)alloc((size_t)B_ * NC_ * DIN_ * DST_ * 4);
  float* Pf = (float*)alloc((size_t)B_ * NC_ * DIN_ * DST_ * 4);
  bf16* w_in = (bf16*)alloc(262144 * 2);
  bf16* w_xp = (bf16*)alloc(24576 * 2);
  bf16* w_dt = (bf16*)alloc(8192 * 2);
  bf16* w_op = (bf16*)alloc(131072 * 2);
  bf16* w_gt = (bf16*)alloc(65536 * 2);
  bf16* y = delta;  // safe alias: p3 reads delta[l,d] then writes y[l,d],
                    // same thread, program order; no cross-thread sharing.

  // 0. weights -> bf16
  wcvt_k<<<1024, 256, 0, stream>>>(in_proj_w, x_proj_w, dt_proj_w, out_proj_w,
                                   gate_w, w_in, w_xp, w_dt, w_op, w_gt);
  // 1. LayerNorm -> bf16
  ln_k<<<M, 256, 0, stream>>>(x, ln_g, ln_b, x_norm);
  // 2. in_proj: xz = x_norm @ in_proj_w^T   (M x 1024, K=256)
  mgemm_k<2, 2, 4, 4, 0><<<dim3(8, 64), 256, 0, stream>>>(
      x_norm, DIM_, w_in, nullptr, xz, 2 * DIN_, M, 2 * DIN_, DIM_, nullptr,
      nullptr);
  // 3. conv + silu -> u
  conv_silu_k<<<(M * DIN_ + 255) / 256, 256, 0, stream>>>(xz, conv_w, conv_b,
                                                          u);
  // 4. x_proj: xdbl = u @ x_proj_w^T   (M x 48, K=512)
  mgemm_k<4, 1, 1, 3, 0><<<dim3(1, 128), 256, 0, stream>>>(
      u, DIN_, w_xp, nullptr, xdbl, 48, M, 48, DIN_, nullptr, nullptr);
  // 5. dt_proj: delta = softplus(xdbl[:,:16] @ dt_proj_w^T + b)  (K=16 pad 32)
  mgemm_k<2, 2, 4, 4, 2><<<dim3(4, 64), 256, 0, stream>>>(
      xdbl, 48, w_dt, dt_proj_b, delta, DIN_, M, DIN_, DTR_, nullptr, nullptr);
  // 6. chunked selective scan (+ D*u + silu(z) gating) -> y
  scan_p1<<<B_ * NC_ * 2, 256, 0, stream>>>(delta, u, xdbl, A_log, hf, Pf);
  scan_p2<<<B_ * DIN_ * DST_ / 256, 256, 0, stream>>>(hf, Pf);
  scan_p3<<<B_ * NC_ * 2, 256, 0, stream>>>(delta, u, xdbl, xz, A_log, Dv, hf,
                                            y);
  // 7. gate = sigmoid(x_norm @ gate_w^T + gate_b)  (M x 256, K=256)
  mgemm_k<2, 2, 4, 4, 1><<<dim3(2, 64), 256, 0, stream>>>(
      x_norm, DIM_, w_gt, gate_b, gate, DIM_, M, DIM_, DIM_, nullptr, nullptr);
  // 8. out = x + (y @ out_proj_w^T) * gate  (M x 256, K=512)
  mgemm_k<2, 2, 4, 4, 3><<<dim3(2, 64), 256, 0, stream>>>(
      y, DIN_, w_op, nullptr, out, DIM_, M, DIM_, DIN_, x, gate);
}

// Round 5
// 252.660 us; speedup vs baseline: 7.4878x; 1.1401x over previous
//
#include <hip/hip_runtime.h>
#include <hip/hip_bf16.h>
#include <math.h>

#define B_ 4
#define L_ 2048
#define DIM_ 256
#define DST_ 16
#define DCONV_ 4
#define DIN_ 512   // D_INNER
#define DTR_ 16    // DT_RANK
#define CHUNK_ 32
#define NC_ (L_ / CHUNK_)  // 64

typedef __attribute__((ext_vector_type(8))) short short8;
typedef __attribute__((ext_vector_type(4))) float floatx4;
typedef __hip_bfloat16 bf16;

__device__ __forceinline__ float softplusf(float v) {
  return (v > 20.f) ? v : log1pf(__expf(v));
}
__device__ __forceinline__ float sigmoidf_(float v) {
  return 1.f / (1.f + __expf(-v));
}

// ---------------- weight fp32 -> bf16 conversion (4 tensors) ----------------
__global__ __launch_bounds__(256) void wcvt_k(
    const float* __restrict__ s0, const float* __restrict__ s1,
    const float* __restrict__ s3, const float* __restrict__ s4,
    bf16* __restrict__ d0, bf16* __restrict__ d1, bf16* __restrict__ d3,
    bf16* __restrict__ d4) {
  int i = blockIdx.x * 256 + threadIdx.x;
  if (i < 262144) d0[i] = __float2bfloat16(s0[i]);  // in_proj_w 1024x256
  if (i < 24576) d1[i] = __float2bfloat16(s1[i]);   // x_proj_w  48x512
  if (i < 131072) d3[i] = __float2bfloat16(s3[i]);  // out_proj_w 256x512
  if (i < 65536) d4[i] = __float2bfloat16(s4[i]);   // gate_w   256x256
}

// ---------------- LayerNorm: one block (256 thr) per row, bf16 out ---------
__global__ __launch_bounds__(256) void ln_k(const float* __restrict__ x,
                                            const float* __restrict__ g,
                                            const float* __restrict__ b,
                                            bf16* __restrict__ out) {
  int row = blockIdx.x;
  int t = threadIdx.x;
  float v = x[(size_t)row * DIM_ + t];
  float s = v, s2 = v * v;
  #pragma unroll
  for (int off = 32; off; off >>= 1) {
    s += __shfl_down(s, off);
    s2 += __shfl_down(s2, off);
  }
  __shared__ float ss[4], ss2[4];
  int w = t >> 6;
  if ((t & 63) == 0) { ss[w] = s; ss2[w] = s2; }
  __syncthreads();
  if (t == 0) {
    float S = ss[0] + ss[1] + ss[2] + ss[3];
    float S2 = ss2[0] + ss2[1] + ss2[2] + ss2[3];
    float mu = S * (1.f / DIM_);
    float var = S2 * (1.f / DIM_) - mu * mu;
    ss[0] = mu;
    ss2[0] = rsqrtf(var + 1e-5f);
  }
  __syncthreads();
  float mu = ss[0], rs = ss2[0];
  out[(size_t)row * DIM_ + t] = __float2bfloat16((v - mu) * rs * g[t] + b[t]);
}

// ---------------- bf16 MFMA GEMM: C = A @ W^T (bf16 out) -------------------
// A: M x K bf16 (row stride lda). W: N x K bf16. 16x16x32 MFMA, fragments
// loaded straight from global (L1/L2 serve the reuse).
template <int BMW, int BNW, int WMT, int WNT>
__global__ __launch_bounds__(256) void mgemm_k(
    const bf16* __restrict__ A, int lda, const bf16* __restrict__ W,
    bf16* __restrict__ Cp, int ldc, int M, int N, int K) {
  constexpr int BM = BMW * WMT * 16;
  constexpr int BN = BNW * WNT * 16;
  int wave = threadIdx.x >> 6;
  int lane = threadIdx.x & 63;
  int wm = wave / BNW, wn = wave % BNW;
  int m_base = blockIdx.y * BM + wm * (WMT * 16);
  int n_base = blockIdx.x * BN + wn * (WNT * 16);
  int lr = lane & 15;
  int quad = lane >> 4;
  const short8 zz = {0, 0, 0, 0, 0, 0, 0, 0};
  floatx4 acc[WMT][WNT];
  #pragma unroll
  for (int i = 0; i < WMT; ++i)
    #pragma unroll
    for (int j = 0; j < WNT; ++j) acc[i][j] = (floatx4){0.f, 0.f, 0.f, 0.f};

  for (int k0 = 0; k0 < K; k0 += 32) {
    int kk = k0 + quad * 8;
    short8 a[WMT], b[WNT];
    #pragma unroll
    for (int i = 0; i < WMT; ++i) {
      const short* p = (const short*)A + (size_t)(m_base + i * 16 + lr) * lda + kk;
      a[i] = *(const short8*)p;
    }
    #pragma unroll
    for (int j = 0; j < WNT; ++j) {
      int n = n_base + j * 16 + lr;
      const short* p = (const short*)W + (size_t)n * K + kk;
      b[j] = (n < N) ? *(const short8*)p : zz;
    }
    #pragma unroll
    for (int i = 0; i < WMT; ++i)
      #pragma unroll
      for (int j = 0; j < WNT; ++j)
        acc[i][j] =
            __builtin_amdgcn_mfma_f32_16x16x32_bf16(a[i], b[j], acc[i][j], 0, 0, 0);
  }

  #pragma unroll
  for (int i = 0; i < WMT; ++i) {
    int m = m_base + i * 16 + quad * 4;
    #pragma unroll
    for (int j = 0; j < WNT; ++j) {
      int n = n_base + j * 16 + lr;
      if (n < N) {
        #pragma unroll
        for (int r = 0; r < 4; ++r)
          Cp[(size_t)(m + r) * ldc + n] = __float2bfloat16(acc[i][j][r]);
      }
    }
  }
}

// ------- fused dual GEMM epilogue: out = x + (y@Wop^T)*sigmoid(xn@Wg^T+b) --
// BM=128 (4 waves: wm in {0,1} x 64 rows... wm=wave>>1 covers 64, WMT=4)
// BN=64 (wn=wave&1, WNT=2). grid (N/64, M/128)
__global__ __launch_bounds__(256) void outgate_k(
    const bf16* __restrict__ y, const bf16* __restrict__ xn,
    const bf16* __restrict__ Wop, const bf16* __restrict__ Wgt,
    const float* __restrict__ gb, const float* __restrict__ x,
    float* __restrict__ out) {
  int wave = threadIdx.x >> 6;
  int lane = threadIdx.x & 63;
  int wm = wave >> 1, wn = wave & 1;
  int m_base = blockIdx.y * 128 + wm * 64;
  int n_base = blockIdx.x * 64 + wn * 32;
  int lr = lane & 15;
  int quad = lane >> 4;
  floatx4 acc1[4][2], acc2[4][2];
  #pragma unroll
  for (int i = 0; i < 4; ++i)
    #pragma unroll
    for (int j = 0; j < 2; ++j) {
      acc1[i][j] = (floatx4){0.f, 0.f, 0.f, 0.f};
      acc2[i][j] = (floatx4){0.f, 0.f, 0.f, 0.f};
    }
  // k0 in [0,256): both GEMMs
  for (int k0 = 0; k0 < 256; k0 += 32) {
    int kk = k0 + quad * 8;
    short8 a1[4], b1[2], a2[4], b2[2];
    #pragma unroll
    for (int i = 0; i < 4; ++i) {
      int m = m_base + i * 16 + lr;
      a1[i] = *(const short8*)((const short*)y + (size_t)m * DIN_ + kk);
      a2[i] = *(const short8*)((const short*)xn + (size_t)m * DIM_ + kk);
    }
    #pragma unroll
    for (int j = 0; j < 2; ++j) {
      int n = n_base + j * 16 + lr;
      b1[j] = *(const short8*)((const short*)Wop + (size_t)n * DIN_ + kk);
      b2[j] = *(const short8*)((const short*)Wgt + (size_t)n * DIM_ + kk);
    }
    #pragma unroll
    for (int i = 0; i < 4; ++i)
      #pragma unroll
      for (int j = 0; j < 2; ++j) {
        acc1[i][j] = __builtin_amdgcn_mfma_f32_16x16x32_bf16(a1[i], b1[j],
                                                             acc1[i][j], 0, 0, 0);
        acc2[i][j] = __builtin_amdgcn_mfma_f32_16x16x32_bf16(a2[i], b2[j],
                                                             acc2[i][j], 0, 0, 0);
      }
  }
  // k0 in [256,512): out_proj only
  for (int k0 = 256; k0 < 512; k0 += 32) {
    int kk = k0 + quad * 8;
    short8 a1[4], b1[2];
    #pragma unroll
    for (int i = 0; i < 4; ++i)
      a1[i] = *(const short8*)((const short*)y +
                               (size_t)(m_base + i * 16 + lr) * DIN_ + kk);
    #pragma unroll
    for (int j = 0; j < 2; ++j)
      b1[j] = *(const short8*)((const short*)Wop +
                               (size_t)(n_base + j * 16 + lr) * DIN_ + kk);
    #pragma unroll
    for (int i = 0; i < 4; ++i)
      #pragma unroll
      for (int j = 0; j < 2; ++j)
        acc1[i][j] = __builtin_amdgcn_mfma_f32_16x16x32_bf16(a1[i], b1[j],
                                                             acc1[i][j], 0, 0, 0);
  }
  #pragma unroll
  for (int i = 0; i < 4; ++i) {
    int m = m_base + i * 16 + quad * 4;
    #pragma unroll
    for (int j = 0; j < 2; ++j) {
      int n = n_base + j * 16 + lr;
      #pragma unroll
      for (int r = 0; r < 4; ++r) {
        size_t idx = (size_t)(m + r) * DIM_ + n;
        float g = sigmoidf_(acc2[i][j][r] + gb[n]);
        out[idx] = x[idx] + acc1[i][j][r] * g;
      }
    }
  }
}

// ---------------- depthwise causal conv (k=4) + SiLU, bf16 io --------------
__global__ __launch_bounds__(256) void conv_silu_k(
    const bf16* __restrict__ xz, const float* __restrict__ cw,
    const float* __restrict__ cb, bf16* __restrict__ u) {
  int idx = blockIdx.x * 256 + threadIdx.x;  // over B*L*DIN
  if (idx >= B_ * L_ * DIN_) return;
  int d = idx & (DIN_ - 1);
  int bl = idx >> 9;  // b*L + l
  int l = bl & (L_ - 1);
  float acc = cb[d];
  #pragma unroll
  for (int k = 0; k < DCONV_; ++k) {
    int ll = l - 3 + k;
    if (ll >= 0)
      acc = fmaf(__bfloat162float(xz[((size_t)(bl - l + ll)) * (2 * DIN_) + d]),
                 cw[d * 4 + k], acc);
  }
  u[idx] = __float2bfloat16(acc / (1.f + __expf(-acc)));  // silu
}

// ------------- chunked selective scan, lane-per-channel, fused dt ----------
// block = 256 threads = 256 channels of one (b, chunk); 2 blocks/(b,chunk).
// blockIdx.x = b*(NC_*2) + c*2 + half. delta computed in-kernel from
// xdbl[:,0:16] (LDS) . dt_proj_w[d,:] (regs) + softplus.

__global__ __launch_bounds__(256) void scan_p1(
    const bf16* __restrict__ u, const bf16* __restrict__ xdbl,
    const float* __restrict__ dtw, const float* __restrict__ dtb,
    const float* __restrict__ A_log, float* __restrict__ hf,
    float* __restrict__ Pf) {
  __shared__ float sX[CHUNK_][48];
  int blk = blockIdx.x;
  int half = blk & 1;
  int c = (blk >> 1) & (NC_ - 1);
  int b = blk >> 7;  // NC_*2 = 128
  int tid = threadIdx.x;
  int d = half * 256 + tid;
  size_t row0 = (size_t)b * L_ + c * CHUNK_;
  for (int idx = tid; idx < CHUNK_ * 48; idx += 256) {
    int l = idx / 48, j = idx - l * 48;
    sX[l][j] = __bfloat162float(xdbl[(row0 + l) * 48 + j]);
  }
  __syncthreads();
  float dw[16];
  #pragma unroll
  for (int r = 0; r < 16; ++r) dw[r] = dtw[d * DTR_ + r];
  float dtbd = dtb[d];
  float Ads[16];
  #pragma unroll
  for (int s = 0; s < 16; ++s) Ads[s] = -__expf(A_log[d * DST_ + s]);
  float h[16];
  #pragma unroll
  for (int s = 0; s < 16; ++s) h[s] = 0.f;
  float cd = 0.f;
  const bf16* up = u + row0 * DIN_ + d;
  for (int l = 0; l < CHUNK_; ++l) {
    float rt = dtbd;
    #pragma unroll
    for (int r = 0; r < 16; ++r) rt = fmaf(dw[r], sX[l][r], rt);
    float dl = softplusf(rt);
    float ul = __bfloat162float(up[(size_t)l * DIN_]);
    cd += dl;
    float dlul = dl * ul;
    #pragma unroll
    for (int s = 0; s < 16; ++s) {
      float dA = __expf(dl * Ads[s]);
      h[s] = fmaf(dA, h[s], sX[l][16 + s] * dlul);
    }
  }
  size_t o = (((size_t)b * NC_ + c) * DIN_ + d) * DST_;
  #pragma unroll
  for (int s = 0; s < 16; ++s) {
    hf[o + s] = h[s];
    Pf[o + s] = __expf(cd * Ads[s]);  // == prod_l exp(dl*Ads)
  }
}

// phase 2: serial combine across chunks, IN-PLACE: hf becomes h0
__global__ __launch_bounds__(256) void scan_p2(float* __restrict__ hf,
                                               const float* __restrict__ Pf) {
  int t = blockIdx.x * 256 + threadIdx.x;  // 0 .. B*DIN*DST-1 (32768)
  int b = t >> 13;
  int ds = t & 8191;
  float h = 0.f;
  #pragma unroll 8
  for (int c = 0; c < NC_; ++c) {
    size_t idx = (((size_t)b * NC_ + c) << 13) + ds;
    float hfc = hf[idx];
    float p = Pf[idx];
    hf[idx] = h;  // h0 for chunk c
    h = fmaf(p, h, hfc);
  }
}

// phase 3: re-scan from h0 (in hf), write gated y (y aliases u: same
// thread reads u[l,d] then overwrites it — program order, race-free)
__global__ __launch_bounds__(256) void scan_p3(
    const bf16* __restrict__ u, const bf16* __restrict__ xdbl,
    const bf16* __restrict__ xz, const float* __restrict__ dtw,
    const float* __restrict__ dtb, const float* __restrict__ A_log,
    const float* __restrict__ Dv, const float* __restrict__ h0,
    bf16* __restrict__ y) {
  __shared__ float sX[CHUNK_][48];
  int blk = blockIdx.x;
  int half = blk & 1;
  int c = (blk >> 1) & (NC_ - 1);
  int b = blk >> 7;
  int tid = threadIdx.x;
  int d = half * 256 + tid;
  size_t row0 = (size_t)b * L_ + c * CHUNK_;
  for (int idx = tid; idx < CHUNK_ * 48; idx += 256) {
    int l = idx / 48, j = idx - l * 48;
    sX[l][j] = __bfloat162float(xdbl[(row0 + l) * 48 + j]);
  }
  __syncthreads();
  float dw[16];
  #pragma unroll
  for (int r = 0; r < 16; ++r) dw[r] = dtw[d * DTR_ + r];
  float dtbd = dtb[d];
  float Ads[16];
  #pragma unroll
  for (int s = 0; s < 16; ++s) Ads[s] = -__expf(A_log[d * DST_ + s]);
  float Dd = Dv[d];
  size_t o = (((size_t)b * NC_ + c) * DIN_ + d) * DST_;
  float h[16];
  #pragma unroll
  for (int s = 0; s < 16; ++s) h[s] = h0[o + s];
  const bf16* up = u + row0 * DIN_ + d;
  const bf16* zp = xz + row0 * (2 * DIN_) + DIN_ + d;
  bf16* yp = y + row0 * DIN_ + d;
  for (int l = 0; l < CHUNK_; ++l) {
    float rt = dtbd;
    #pragma unroll
    for (int r = 0; r < 16; ++r) rt = fmaf(dw[r], sX[l][r], rt);
    float dl = softplusf(rt);
    float ul = __bfloat162float(up[(size_t)l * DIN_]);
    float z = __bfloat162float(zp[(size_t)l * (2 * DIN_)]);
    float dlul = dl * ul;
    float py = 0.f;
    #pragma unroll
    for (int s = 0; s < 16; ++s) {
      float dA = __expf(dl * Ads[s]);
      h[s] = fmaf(dA, h[s], sX[l][16 + s] * dlul);
      py = fmaf(h[s], sX[l][32 + s], py);
    }
    float sil = z * sigmoidf_(z);
    yp[(size_t)l * DIN_] = __float2bfloat16((py + Dd * ul) * sil);
  }
}

extern "C" void kernel_launch(void* const* d_in, const int* in_sizes, int n_in,
                              void* d_out, int out_size, void* d_ws,
                              size_t ws_size, hipStream_t stream) {
  const float* x = (const float*)d_in[0];
  const float* ln_g = (const float*)d_in[1];
  const float* ln_b = (const float*)d_in[2];
  const float* in_proj_w = (const float*)d_in[3];
  const float* conv_w = (const float*)d_in[4];
  const float* conv_b = (const float*)d_in[5];
  const float* x_proj_w = (const float*)d_in[6];
  const float* dt_proj_w = (const float*)d_in[7];
  const float* dt_proj_b = (const float*)d_in[8];
  const float* A_log = (const float*)d_in[9];
  const float* Dv = (const float*)d_in[10];
  const float* out_proj_w = (const float*)d_in[11];
  const float* gate_w = (const float*)d_in[12];
  const float* gate_b = (const float*)d_in[13];
  float* out = (float*)d_out;

  const int M = B_ * L_;  // 8192
  char* w = (char*)d_ws;
  auto alloc = [&](size_t bytes) {
    void* p = w;
    w += (bytes + 255) & ~(size_t)255;
    return p;
  };
  bf16* x_norm = (bf16*)alloc((size_t)M * DIM_ * 2);
  bf16* xz = (bf16*)alloc((size_t)M * 2 * DIN_ * 2);
  bf16* u = (bf16*)alloc((size_t)M * DIN_ * 2);  // y aliases u in p3
  bf16* xdbl = (bf16*)alloc((size_t)M * 48 * 2);
  float* hf = (float*)alloc((size_t)B_ * NC_ * DIN_ * DST_ * 4);
  float* Pf = (float*)alloc((size_t)B_ * NC_ * DIN_ * DST_ * 4);
  bf16* w_in = (bf16*)alloc(262144 * 2);
  bf16* w_xp = (bf16*)alloc(24576 * 2);
  bf16* w_op = (bf16*)alloc(131072 * 2);
  bf16* w_gt = (bf16*)alloc(65536 * 2);
  bf16* y = u;

  // 0. weights -> bf16
  wcvt_k<<<1024, 256, 0, stream>>>(in_proj_w, x_proj_w, out_proj_w, gate_w,
                                   w_in, w_xp, w_op, w_gt);
  // 1. LayerNorm -> bf16
  ln_k<<<M, 256, 0, stream>>>(x, ln_g, ln_b, x_norm);
  // 2. in_proj: xz = x_norm @ in_proj_w^T   (M x 1024, K=256)
  mgemm_k<2, 2, 4, 4><<<dim3(8, 64), 256, 0, stream>>>(
      x_norm, DIM_, w_in, xz, 2 * DIN_, M, 2 * DIN_, DIM_);
  // 3. conv + silu -> u
  conv_silu_k<<<(M * DIN_ + 255) / 256, 256, 0, stream>>>(xz, conv_w, conv_b,
                                                          u);
  // 4. x_proj: xdbl = u @ x_proj_w^T   (M x 48, K=512)
  mgemm_k<4, 1, 1, 3><<<dim3(1, 128), 256, 0, stream>>>(u, DIN_, w_xp, xdbl,
                                                        48, M, 48, DIN_);
  // 5-6. chunked selective scan with fused dt_proj+softplus -> y (=u)
  scan_p1<<<B_ * NC_ * 2, 256, 0, stream>>>(u, xdbl, dt_proj_w, dt_proj_b,
                                            A_log, hf, Pf);
  scan_p2<<<B_ * DIN_ * DST_ / 256, 256, 0, stream>>>(hf, Pf);
  scan_p3<<<B_ * NC_ * 2, 256, 0, stream>>>(u, xdbl, xz, dt_proj_w, dt_proj_b,
                                            A_log, Dv, hf, y);
  // 7. out = x + (y @ out_proj_w^T) * sigmoid(x_norm @ gate_w^T + gate_b)
  outgate_k<<<dim3(DIM_ / 64, M / 128), 256, 0, stream>>>(
      y, x_norm, w_op, w_gt, gate_b, x, out);
}